// Round 5
// baseline (288.092 us; speedup 1.0000x reference)
//
#include <hip/hip_runtime.h>
#include <hip/hip_bf16.h>
#include <cstdint>
#include <cstddef>

// Shapes (fixed): B=8, S=512, E=H=2048.
#define RTOT 4096      // B*S rows
#define DIM  2048
#define NCAT 6144      // f | c | g column sections
#define NCHUNK 32      // scan chunks
#define TCHUNK 16      // timesteps per chunk
#define NT 32          // K-tiles per GEMM (2048/64)

typedef __attribute__((ext_vector_type(4))) int int4v;

__device__ __forceinline__ float fast_sigmoid(float z) {
    return __builtin_amdgcn_rcpf(1.0f + __expf(-z));
}
__device__ __forceinline__ unsigned short f2h(float f) {
    union { _Float16 h; unsigned short u; } v; v.h = (_Float16)f; return v.u;
}
__device__ __forceinline__ float h2f(unsigned short u) {
    union { _Float16 h; unsigned short u; } v; v.u = u; return (float)v.h;
}

// global -> LDS DMA, 16B/lane; dest = wave-uniform base + lane*16.
#define GLDS(gp, lp) __builtin_amdgcn_global_load_lds( \
    (__attribute__((address_space(1))) const void*)(gp), \
    (__attribute__((address_space(3))) void*)(lp), 16, 0, 0)

// LDS[r][slot s] = G[r][s ^ ((r>>1)&3)]  (0 bank conflicts, verified)
__device__ __forceinline__ int4v frag_ld(const signed char* p, int R, int lq) {
    return *(const int4v*)(p + R * 64 + ((lq ^ ((R >> 1) & 3)) * 16));
}

// ---------------------------------------------------------------------------
// prep_all: one branched kernel (unchanged from R2).
__global__ __launch_bounds__(256) void prep_all(
    const float* __restrict__ x, const float* __restrict__ scale,
    const float* __restrict__ Wf, const float* __restrict__ Wc,
    const float* __restrict__ Wg,
    signed char* __restrict__ WcatT, signed char* __restrict__ Wgb,
    signed char* __restrict__ Xq, signed char* __restrict__ Q1,
    signed char* __restrict__ Q2, float* __restrict__ s_arr,
    float* __restrict__ s1_arr)
{
    __shared__ __align__(16) char smem[4224];
    int bid = blockIdx.x;
    int tid = threadIdx.x;
    if (bid < 3072) {
        signed char (*tile)[65] = (signed char(*)[65])smem;
        int j0 = (bid % 96) * 64;
        int k0 = (bid / 96) * 64;
        const float* W = (j0 < 2048) ? Wf : (j0 < 4096) ? Wc : Wg;
        int jb = j0 & 2047;
        int c  = tid & 63;
        int rr = tid >> 6;
#pragma unroll
        for (int p = 0; p < 16; ++p) {
            int kl = p * 4 + rr;
            tile[kl][c] = (signed char)(int)W[(size_t)(k0 + kl) * DIM + jb + c];
        }
        __syncthreads();
#pragma unroll
        for (int p = 0; p < 16; ++p) {
            int jl = p * 4 + rr;
            WcatT[(size_t)(j0 + jl) * DIM + k0 + c] = tile[c][jl];
        }
    } else if (bid < 4096) {
        int idx = (bid - 3072) * 4096 + tid * 16;
#pragma unroll
        for (int p = 0; p < 4; ++p) {
            float4 v = *(const float4*)(Wg + idx + p * 4);
            char4 o;
            o.x = (signed char)(int)v.x; o.y = (signed char)(int)v.y;
            o.z = (signed char)(int)v.z; o.w = (signed char)(int)v.w;
            *(char4*)(Wgb + idx + p * 4) = o;
        }
    } else {
        // one wave per row; 32 elems/lane; shuffle-only butterfly reductions
        int row = (bid - 4096) * 4 + (tid >> 6);
        int lane = tid & 63;
        const float* xr = x + (size_t)row * DIM;
        float xs[32], ys[32];
        float sum = 0.f, mx2 = 0.f;
#pragma unroll
        for (int sw = 0; sw < 4; ++sw) {
            int base = sw * 512 + lane * 8;
            float4 a0 = *(const float4*)(xr + base);
            float4 a1 = *(const float4*)(xr + base + 4);
            xs[sw * 8 + 0] = a0.x; xs[sw * 8 + 1] = a0.y;
            xs[sw * 8 + 2] = a0.z; xs[sw * 8 + 3] = a0.w;
            xs[sw * 8 + 4] = a1.x; xs[sw * 8 + 5] = a1.y;
            xs[sw * 8 + 6] = a1.z; xs[sw * 8 + 7] = a1.w;
        }
#pragma unroll
        for (int i = 0; i < 32; ++i) {
            sum += xs[i] * xs[i];
            mx2 = fmaxf(mx2, fabsf(xs[i]));
        }
#pragma unroll
        for (int off = 1; off < 64; off <<= 1) {
            sum += __shfl_xor(sum, off);
            mx2 = fmaxf(mx2, __shfl_xor(mx2, off));
        }
        float rms = 1.0f / sqrtf(sum * (1.0f / 2048.0f) + 1e-5f);
        float mx = 0.f;
#pragma unroll
        for (int sw = 0; sw < 4; ++sw) {
            int base = sw * 512 + lane * 8;
            float4 c0 = *(const float4*)(scale + base);
            float4 c1 = *(const float4*)(scale + base + 4);
            float scv[8] = {c0.x, c0.y, c0.z, c0.w, c1.x, c1.y, c1.z, c1.w};
#pragma unroll
            for (int i = 0; i < 8; ++i) {
                float yv = (xs[sw * 8 + i] * rms) * scv[i];
                ys[sw * 8 + i] = yv;
                mx = fmaxf(mx, fabsf(yv));
            }
        }
#pragma unroll
        for (int off = 1; off < 64; off <<= 1) mx = fmaxf(mx, __shfl_xor(mx, off));
        float s = 127.0f / (mx + 1e-5f);
        s = fminf(fmaxf(s, 0.001f), 1000.0f);
        float s1 = 127.0f / (mx2 + 1e-5f);
        float inv_s1 = 1.0f / s1;
        if (lane == 0) { s_arr[row] = s; s1_arr[row] = s1; }
#pragma unroll
        for (int sw = 0; sw < 4; ++sw) {
            signed char q8[8], q1b[8], q2b[8];
#pragma unroll
            for (int i = 0; i < 8; ++i) {
                float xv = xs[sw * 8 + i];
                float q = fminf(fmaxf(rintf(s * ys[sw * 8 + i]), -128.f), 127.f);
                q8[i] = (signed char)(int)q;
                float qq1 = fminf(fmaxf(rintf(s1 * xv), -128.f), 127.f);
                q1b[i] = (signed char)(int)qq1;
                float r = xv - qq1 * inv_s1;
                float qq2 = fminf(fmaxf(rintf(s1 * 256.f * r), -128.f), 127.f);
                q2b[i] = (signed char)(int)qq2;
            }
            size_t o = (size_t)row * DIM + sw * 512 + lane * 8;
            *(int2*)(Xq + o) = *(int2*)q8;
            *(int2*)(Q1 + o) = *(int2*)q1b;
            *(int2*)(Q2 + o) = *(int2*)q2b;
        }
    }
}

// ---------------------------------------------------------------------------
// gemm_all — CO-RESIDENCY version: 256 threads (4 waves), 64-reg accumulators,
// 48 KB LDS (2-deep ring) => 3 independent blocks per CU. One barrier per
// K-tile; per-wave vmcnt(0) BEFORE the barrier guarantees all waves' staged
// tile landed. Latency events are covered by the other co-resident blocks
// (m114 wave-level overlap), not by intra-block scheduling.
//   fcg: 128x128 tile, waves 2x2 of 64x64. 1536 blocks.
//   cg : 128x64 tile, waves 2x2 of 64x32, two i8 planes. 1024 blocks.
//   grid interleaved 3:2 (groups of 5) = 2560 blocks.
__global__ __launch_bounds__(256, 3) void gemm_all(
    const signed char* __restrict__ Xq, const signed char* __restrict__ WcatT,
    const signed char* __restrict__ Q1, const signed char* __restrict__ Q2,
    const signed char* __restrict__ Wgb,
    const float* __restrict__ s_arr, const float* __restrict__ s1_arr,
    const float* __restrict__ b_f, const float* __restrict__ b_c,
    const float* __restrict__ b_g,
    unsigned short* __restrict__ FCG,   // (4096 x 6144) fp16
    unsigned short* __restrict__ U,     // cg*x  fp16
    unsigned short* __restrict__ V)     // 1-cg  fp16
{
    extern __shared__ __align__(16) signed char lds[];
    int bid = blockIdx.x;
    int grp = bid / 5, r5 = bid % 5;
    int tid = threadIdx.x;
    int lane = tid & 63, wv = tid >> 6;          // 4 waves
    int lr = lane & 15, lq = lane >> 4;
    // staging: wave wv covers rows [wv*16, wv*16+16) of each 64-row unit;
    // source column pre-swizzled so LDS[r][s] = G[r][s ^ ((r>>1)&3)].
    int srow = wv * 16 + (lane >> 2);            // 0..63
    int ssw  = ((lane & 3) ^ ((srow >> 1) & 3)) * 16;
    const size_t ustep = (size_t)64 * DIM;       // +64 rows: (r>>1)&3 invariant

    if (r5 < 3) {
        // ---- fcg: 128x128 tile; buf = A 8KB | B 8KB; ring stride 16384 ----
        int fb = grp * 3 + r5;                   // 0..1535
        int m0 = (fb & 31) * 128;
        int n0 = (fb >> 5) * 128;                // 48 n-tiles
        int wm = (wv >> 1) * 64, wn = (wv & 1) * 64;
        const signed char* gA = Xq + (size_t)(m0 + srow) * DIM + ssw;
        const signed char* gB = WcatT + (size_t)(n0 + srow) * DIM + ssw;

        int4v acc[4][4] = {};
        int4v a[4], b[4];

        // prologue: tile 0 -> buf0 (4 loads/wave)
        GLDS(gA,         lds + wv * 1024);
        GLDS(gA + ustep, lds + 4096 + wv * 1024);
        GLDS(gB,         lds + 8192 + wv * 1024);
        GLDS(gB + ustep, lds + 12288 + wv * 1024);

        for (int t = 0; t < NT; ++t) {
            // own staged loads landed; barrier => ALL waves' loads landed
            asm volatile("s_waitcnt vmcnt(0)" ::: "memory");
            __builtin_amdgcn_sched_barrier(0);
            __builtin_amdgcn_s_barrier();
            __builtin_amdgcn_sched_barrier(0);
            const signed char* cur = lds + (t & 1) * 16384;
            signed char* nxt = lds + ((t + 1) & 1) * 16384;
#pragma unroll
            for (int i = 0; i < 4; ++i) a[i] = frag_ld(cur, wm + i * 16 + lr, lq);
#pragma unroll
            for (int j = 0; j < 4; ++j) b[j] = frag_ld(cur + 8192, wn + j * 16 + lr, lq);
            if (t + 1 < NT) {
                int kt = (t + 1) * 64;
                GLDS(gA + kt,         nxt + wv * 1024);
                GLDS(gA + ustep + kt, nxt + 4096 + wv * 1024);
                GLDS(gB + kt,         nxt + 8192 + wv * 1024);
                GLDS(gB + ustep + kt, nxt + 12288 + wv * 1024);
            }
            asm volatile("s_waitcnt lgkmcnt(0)" ::: "memory");
            __builtin_amdgcn_sched_barrier(0);
            __builtin_amdgcn_s_setprio(1);
#pragma unroll
            for (int i = 0; i < 4; ++i)
#pragma unroll
                for (int j = 0; j < 4; ++j)
                    acc[i][j] = __builtin_amdgcn_mfma_i32_16x16x64_i8(
                        a[i], b[j], acc[i][j], 0, 0, 0);
            __builtin_amdgcn_s_setprio(0);
        }

        // epilogue (math identical to verified kernel)
        int rowb = m0 + wm;
#pragma unroll
        for (int mi = 0; mi < 4; ++mi) {
            float rinv[4];
#pragma unroll
            for (int r = 0; r < 4; ++r)
                rinv[r] = __builtin_amdgcn_rcpf(s_arr[rowb + mi * 16 + lq * 4 + r]);
#pragma unroll
            for (int ni = 0; ni < 4; ++ni) {
                int gcol = n0 + wn + ni * 16 + lr;
                int sec = gcol >> 11;
                int jj = gcol & 2047;
                float bias = (sec == 0) ? b_f[jj] : (sec == 1) ? b_c[jj] : b_g[jj];
#pragma unroll
                for (int r = 0; r < 4; ++r) {
                    int grow = rowb + mi * 16 + lq * 4 + r;
                    float z = fmaf((float)acc[mi][ni][r], rinv[r], bias);
                    float sg = fast_sigmoid(z);
                    FCG[(size_t)grow * NCAT + gcol] = f2h((sec == 1) ? z * sg : sg);
                }
            }
        }
    } else {
        // ---- cg: 128x64 tile, two planes; buf = A1 8K | A2 8K | B 4K;
        //      ring stride 20480 ----
        int cb = grp * 2 + (r5 - 3);             // 0..1023
        int m0 = (cb & 31) * 128;
        int n0 = (cb >> 5) * 64;                 // 32 n-tiles
        int wm = (wv >> 1) * 64, wn = (wv & 1) * 32;
        const signed char* g1 = Q1 + (size_t)(m0 + srow) * DIM + ssw;
        const signed char* g2 = Q2 + (size_t)(m0 + srow) * DIM + ssw;
        const signed char* gB = Wgb + (size_t)(n0 + srow) * DIM + ssw; // srow<64

        int4v acc1[4][2] = {};
        int4v acc2[4][2] = {};
        int4v a1[4], a2[4], b[2];

        // prologue: tile 0 -> buf0 (5 loads/wave)
        GLDS(g1,         lds + wv * 1024);
        GLDS(g1 + ustep, lds + 4096 + wv * 1024);
        GLDS(g2,         lds + 8192 + wv * 1024);
        GLDS(g2 + ustep, lds + 12288 + wv * 1024);
        GLDS(gB,         lds + 16384 + wv * 1024);

        for (int t = 0; t < NT; ++t) {
            asm volatile("s_waitcnt vmcnt(0)" ::: "memory");
            __builtin_amdgcn_sched_barrier(0);
            __builtin_amdgcn_s_barrier();
            __builtin_amdgcn_sched_barrier(0);
            const signed char* cur = lds + (t & 1) * 20480;
            signed char* nxt = lds + ((t + 1) & 1) * 20480;
#pragma unroll
            for (int i = 0; i < 4; ++i) {
                a1[i] = frag_ld(cur, wm + i * 16 + lr, lq);
                a2[i] = frag_ld(cur + 8192, wm + i * 16 + lr, lq);
            }
#pragma unroll
            for (int j = 0; j < 2; ++j) b[j] = frag_ld(cur + 16384, wn + j * 16 + lr, lq);
            if (t + 1 < NT) {
                int kt = (t + 1) * 64;
                GLDS(g1 + kt,         nxt + wv * 1024);
                GLDS(g1 + ustep + kt, nxt + 4096 + wv * 1024);
                GLDS(g2 + kt,         nxt + 8192 + wv * 1024);
                GLDS(g2 + ustep + kt, nxt + 12288 + wv * 1024);
                GLDS(gB + kt,         nxt + 16384 + wv * 1024);
            }
            asm volatile("s_waitcnt lgkmcnt(0)" ::: "memory");
            __builtin_amdgcn_sched_barrier(0);
            __builtin_amdgcn_s_setprio(1);
#pragma unroll
            for (int i = 0; i < 4; ++i)
#pragma unroll
                for (int j = 0; j < 2; ++j) {
                    acc1[i][j] = __builtin_amdgcn_mfma_i32_16x16x64_i8(
                        a1[i], b[j], acc1[i][j], 0, 0, 0);
                    acc2[i][j] = __builtin_amdgcn_mfma_i32_16x16x64_i8(
                        a2[i], b[j], acc2[i][j], 0, 0, 0);
                }
            __builtin_amdgcn_s_setprio(0);
        }

        // epilogue (math identical to verified kernel)
        int rowb = m0 + wm;
#pragma unroll
        for (int mi = 0; mi < 4; ++mi) {
            float rinv[4];
#pragma unroll
            for (int r = 0; r < 4; ++r)
                rinv[r] = __builtin_amdgcn_rcpf(s1_arr[rowb + mi * 16 + lq * 4 + r]);
#pragma unroll
            for (int ni = 0; ni < 2; ++ni) {
                int gcol = n0 + wn + ni * 16 + lr;
#pragma unroll
                for (int r = 0; r < 4; ++r) {
                    int grow = rowb + mi * 16 + lq * 4 + r;
                    size_t go = (size_t)grow * DIM + gcol;
                    float zs = (float)acc1[mi][ni][r] + (float)acc2[mi][ni][r] * (1.f / 256.f);
                    float cg = fast_sigmoid(zs * rinv[r]);
                    float xv = ((float)Q1[go] + (float)Q2[go] * (1.f / 256.f)) * rinv[r];
                    U[go] = f2h(cg * xv);
                    V[go] = f2h(1.f - cg);
                }
            }
        }
    }
}

// ---------------------------------------------------------------------------
// Scan phase 1: 2 chains/thread, TCHUNK=16 (992 blocks; last chunk's summary
// is never consumed, so grid.y = NCHUNK-1).
__global__ __launch_bounds__(256) void scan_partial(
    const unsigned short* __restrict__ FCG, const unsigned short* __restrict__ U,
    const unsigned short* __restrict__ V, float4* __restrict__ PQ4)
{
    int tp = blockIdx.x * 256 + threadIdx.x;   // pair 0..1023
    int c = blockIdx.y;
    int b = blockIdx.z;
    int h0 = tp * 2;
    size_t r0 = (size_t)(b * 512 + c * TCHUNK);
    const unsigned short* fp = FCG + r0 * NCAT + h0;
    const unsigned short* up = U + r0 * DIM + h0;
    const unsigned short* vp = V + r0 * DIM + h0;
    float P0 = 1.f, Q0 = 0.f, P1 = 1.f, Q1v = 0.f;
#pragma unroll 4
    for (int t = 0; t < TCHUNK; ++t) {
        unsigned fw = *(const unsigned*)(fp);
        unsigned cw = *(const unsigned*)(fp + 2048);
        unsigned uw = *(const unsigned*)(up);
        unsigned vw = *(const unsigned*)(vp);
        float f0 = h2f(fw & 0xffff), f1 = h2f(fw >> 16);
        float c0 = h2f(cw & 0xffff), c1 = h2f(cw >> 16);
        float u0 = h2f(uw & 0xffff), u1 = h2f(uw >> 16);
        float v0 = h2f(vw & 0xffff), v1 = h2f(vw >> 16);
        float A0 = v0 * f0, A1 = v1 * f1;
        float B0 = fmaf(v0 * (1.f - f0), c0, u0);
        float B1 = fmaf(v1 * (1.f - f1), c1, u1);
        P0 = A0 * P0; Q0 = fmaf(A0, Q0, B0);
        P1 = A1 * P1; Q1v = fmaf(A1, Q1v, B1);
        fp += NCAT; up += DIM; vp += DIM;
    }
    float4 o; o.x = P0; o.y = Q0; o.z = P1; o.w = Q1v;
    PQ4[(size_t)c * 8192 + b * 1024 + tp] = o;
}

// Scan phase 3: recombine chunk summaries, then replay TCHUNK=16 steps and
// emit o_t (fp32).
__global__ __launch_bounds__(256) void scan_final(
    const unsigned short* __restrict__ FCG, const unsigned short* __restrict__ U,
    const unsigned short* __restrict__ V, const float4* __restrict__ PQ4,
    float* __restrict__ out)
{
    int tp = blockIdx.x * 256 + threadIdx.x;
    int c = blockIdx.y;
    int b = blockIdx.z;
    int h0 = tp * 2;
    float h0s = 0.f, h1s = 0.f;
#pragma unroll 4
    for (int cc = 0; cc < c; ++cc) {
        float4 pq = PQ4[(size_t)cc * 8192 + b * 1024 + tp];
        h0s = fmaf(pq.x, h0s, pq.y);
        h1s = fmaf(pq.z, h1s, pq.w);
    }
    size_t r0 = (size_t)(b * 512 + c * TCHUNK);
    const unsigned short* fp = FCG + r0 * NCAT + h0;
    const unsigned short* up = U + r0 * DIM + h0;
    const unsigned short* vp = V + r0 * DIM + h0;
    float* op = out + r0 * DIM + h0;
#pragma unroll 4
    for (int t = 0; t < TCHUNK; ++t) {
        unsigned fw = *(const unsigned*)(fp);
        unsigned cw = *(const unsigned*)(fp + 2048);
        unsigned gw = *(const unsigned*)(fp + 4096);
        unsigned uw = *(const unsigned*)(up);
        unsigned vw = *(const unsigned*)(vp);
        float f0 = h2f(fw & 0xffff), f1 = h2f(fw >> 16);
        float c0 = h2f(cw & 0xffff), c1 = h2f(cw >> 16);
        float g0 = h2f(gw & 0xffff), g1 = h2f(gw >> 16);
        float u0 = h2f(uw & 0xffff), u1 = h2f(uw >> 16);
        float v0 = h2f(vw & 0xffff), v1 = h2f(vw >> 16);
        float hn0 = f0 * h0s + (1.f - f0) * c0;
        float hn1 = f1 * h1s + (1.f - f1) * c1;
        float2 ov; ov.x = g0 * hn0; ov.y = g1 * hn1;
        *(float2*)op = ov;
        h0s = fmaf(v0, hn0, u0);
        h1s = fmaf(v1, hn1, u1);
        fp += NCAT; up += DIM; vp += DIM; op += DIM;
    }
}

// ---------------------------------------------------------------------------
extern "C" void kernel_launch(void* const* d_in, const int* in_sizes, int n_in,
                              void* d_out, int out_size, void* d_ws, size_t ws_size,
                              hipStream_t stream) {
    const float* x     = (const float*)d_in[0];
    const float* rmssc = (const float*)d_in[1];
    const float* W_f   = (const float*)d_in[2];
    const float* W_c   = (const float*)d_in[3];
    const float* W_g   = (const float*)d_in[4];
    const float* b_f   = (const float*)d_in[5];
    const float* b_c   = (const float*)d_in[6];
    const float* b_g   = (const float*)d_in[7];
    float* out = (float*)d_out;

    char* ws = (char*)d_ws;
    size_t off = 0;
    auto alloc = [&](size_t bytes) -> void* {
        void* p = ws + off;
        off += (bytes + 255) & ~(size_t)255;
        return p;
    };
    signed char* WcatT = (signed char*)alloc((size_t)NCAT * DIM);
    signed char* Wgb   = (signed char*)alloc((size_t)DIM * DIM);
    signed char* Xq    = (signed char*)alloc((size_t)RTOT * DIM);
    signed char* Q1    = (signed char*)alloc((size_t)RTOT * DIM);
    signed char* Q2    = (signed char*)alloc((size_t)RTOT * DIM);
    float* s_arr       = (float*)alloc((size_t)RTOT * 4);
    float* s1_arr      = (float*)alloc((size_t)RTOT * 4);
    unsigned short* FCG = (unsigned short*)alloc((size_t)RTOT * NCAT * 2);
    unsigned short* U   = (unsigned short*)alloc((size_t)RTOT * DIM * 2);
    unsigned short* V   = (unsigned short*)alloc((size_t)RTOT * DIM * 2);
    float4* PQ4        = (float4*)alloc((size_t)NCHUNK * 8192 * 16);

    hipLaunchKernelGGL(prep_all, dim3(5120), dim3(256), 0, stream,
                       x, rmssc, W_f, W_c, W_g, WcatT, Wgb, Xq, Q1, Q2,
                       s_arr, s1_arr);
    hipLaunchKernelGGL(gemm_all, dim3(2560), dim3(256), 49152, stream,
                       Xq, WcatT, Q1, Q2, Wgb, s_arr, s1_arr,
                       b_f, b_c, b_g, FCG, U, V);
    hipLaunchKernelGGL(scan_partial, dim3(DIM / 512, NCHUNK - 1, 8), dim3(256), 0, stream,
                       FCG, U, V, PQ4);
    hipLaunchKernelGGL(scan_final, dim3(DIM / 512, NCHUNK, 8), dim3(256), 0, stream,
                       FCG, U, V, PQ4, out);
}

// Round 6
// 270.622 us; speedup vs baseline: 1.0646x; 1.0646x over previous
//
#include <hip/hip_runtime.h>
#include <hip/hip_bf16.h>
#include <cstdint>
#include <cstddef>

// Shapes (fixed): B=8, S=512, E=H=2048.
#define RTOT 4096      // B*S rows
#define DIM  2048
#define NCAT 6144      // f | c | g column sections
#define NCHUNK 32      // scan chunks
#define TCHUNK 16      // timesteps per chunk
#define NT 32          // K-tiles per GEMM (2048/64)

typedef __attribute__((ext_vector_type(4))) int int4v;

__device__ __forceinline__ float fast_sigmoid(float z) {
    return __builtin_amdgcn_rcpf(1.0f + __expf(-z));
}
__device__ __forceinline__ unsigned short f2h(float f) {
    union { _Float16 h; unsigned short u; } v; v.h = (_Float16)f; return v.u;
}
__device__ __forceinline__ float h2f(unsigned short u) {
    union { _Float16 h; unsigned short u; } v; v.u = u; return (float)v.h;
}

// global -> LDS DMA, 16B/lane; dest = wave-uniform base + lane*16.
#define GLDS(gp, lp) __builtin_amdgcn_global_load_lds( \
    (__attribute__((address_space(1))) const void*)(gp), \
    (__attribute__((address_space(3))) void*)(lp), 16, 0, 0)

// LDS[r][slot s] = G[r][s ^ ((r>>1)&3)]  (0 bank conflicts, verified)
__device__ __forceinline__ int4v frag_ld(const signed char* p, int R, int lq) {
    return *(const int4v*)(p + R * 64 + ((lq ^ ((R >> 1) & 3)) * 16));
}

// ---------------------------------------------------------------------------
// prep_all: one branched kernel (unchanged).
__global__ __launch_bounds__(256) void prep_all(
    const float* __restrict__ x, const float* __restrict__ scale,
    const float* __restrict__ Wf, const float* __restrict__ Wc,
    const float* __restrict__ Wg,
    signed char* __restrict__ WcatT, signed char* __restrict__ Wgb,
    signed char* __restrict__ Xq, signed char* __restrict__ Q1,
    signed char* __restrict__ Q2, float* __restrict__ s_arr,
    float* __restrict__ s1_arr)
{
    __shared__ __align__(16) char smem[4224];
    int bid = blockIdx.x;
    int tid = threadIdx.x;
    if (bid < 3072) {
        signed char (*tile)[65] = (signed char(*)[65])smem;
        int j0 = (bid % 96) * 64;
        int k0 = (bid / 96) * 64;
        const float* W = (j0 < 2048) ? Wf : (j0 < 4096) ? Wc : Wg;
        int jb = j0 & 2047;
        int c  = tid & 63;
        int rr = tid >> 6;
#pragma unroll
        for (int p = 0; p < 16; ++p) {
            int kl = p * 4 + rr;
            tile[kl][c] = (signed char)(int)W[(size_t)(k0 + kl) * DIM + jb + c];
        }
        __syncthreads();
#pragma unroll
        for (int p = 0; p < 16; ++p) {
            int jl = p * 4 + rr;
            WcatT[(size_t)(j0 + jl) * DIM + k0 + c] = tile[c][jl];
        }
    } else if (bid < 4096) {
        int idx = (bid - 3072) * 4096 + tid * 16;
#pragma unroll
        for (int p = 0; p < 4; ++p) {
            float4 v = *(const float4*)(Wg + idx + p * 4);
            char4 o;
            o.x = (signed char)(int)v.x; o.y = (signed char)(int)v.y;
            o.z = (signed char)(int)v.z; o.w = (signed char)(int)v.w;
            *(char4*)(Wgb + idx + p * 4) = o;
        }
    } else {
        // one wave per row; 32 elems/lane; shuffle-only butterfly reductions
        int row = (bid - 4096) * 4 + (tid >> 6);
        int lane = tid & 63;
        const float* xr = x + (size_t)row * DIM;
        float xs[32], ys[32];
        float sum = 0.f, mx2 = 0.f;
#pragma unroll
        for (int sw = 0; sw < 4; ++sw) {
            int base = sw * 512 + lane * 8;
            float4 a0 = *(const float4*)(xr + base);
            float4 a1 = *(const float4*)(xr + base + 4);
            xs[sw * 8 + 0] = a0.x; xs[sw * 8 + 1] = a0.y;
            xs[sw * 8 + 2] = a0.z; xs[sw * 8 + 3] = a0.w;
            xs[sw * 8 + 4] = a1.x; xs[sw * 8 + 5] = a1.y;
            xs[sw * 8 + 6] = a1.z; xs[sw * 8 + 7] = a1.w;
        }
#pragma unroll
        for (int i = 0; i < 32; ++i) {
            sum += xs[i] * xs[i];
            mx2 = fmaxf(mx2, fabsf(xs[i]));
        }
#pragma unroll
        for (int off = 1; off < 64; off <<= 1) {
            sum += __shfl_xor(sum, off);
            mx2 = fmaxf(mx2, __shfl_xor(mx2, off));
        }
        float rms = 1.0f / sqrtf(sum * (1.0f / 2048.0f) + 1e-5f);
        float mx = 0.f;
#pragma unroll
        for (int sw = 0; sw < 4; ++sw) {
            int base = sw * 512 + lane * 8;
            float4 c0 = *(const float4*)(scale + base);
            float4 c1 = *(const float4*)(scale + base + 4);
            float scv[8] = {c0.x, c0.y, c0.z, c0.w, c1.x, c1.y, c1.z, c1.w};
#pragma unroll
            for (int i = 0; i < 8; ++i) {
                float yv = (xs[sw * 8 + i] * rms) * scv[i];
                ys[sw * 8 + i] = yv;
                mx = fmaxf(mx, fabsf(yv));
            }
        }
#pragma unroll
        for (int off = 1; off < 64; off <<= 1) mx = fmaxf(mx, __shfl_xor(mx, off));
        float s = 127.0f / (mx + 1e-5f);
        s = fminf(fmaxf(s, 0.001f), 1000.0f);
        float s1 = 127.0f / (mx2 + 1e-5f);
        float inv_s1 = 1.0f / s1;
        if (lane == 0) { s_arr[row] = s; s1_arr[row] = s1; }
#pragma unroll
        for (int sw = 0; sw < 4; ++sw) {
            signed char q8[8], q1b[8], q2b[8];
#pragma unroll
            for (int i = 0; i < 8; ++i) {
                float xv = xs[sw * 8 + i];
                float q = fminf(fmaxf(rintf(s * ys[sw * 8 + i]), -128.f), 127.f);
                q8[i] = (signed char)(int)q;
                float qq1 = fminf(fmaxf(rintf(s1 * xv), -128.f), 127.f);
                q1b[i] = (signed char)(int)qq1;
                float r = xv - qq1 * inv_s1;
                float qq2 = fminf(fmaxf(rintf(s1 * 256.f * r), -128.f), 127.f);
                q2b[i] = (signed char)(int)qq2;
            }
            size_t o = (size_t)row * DIM + sw * 512 + lane * 8;
            *(int2*)(Xq + o) = *(int2*)q8;
            *(int2*)(Q1 + o) = *(int2*)q1b;
            *(int2*)(Q2 + o) = *(int2*)q2b;
        }
    }
}

// ---------------------------------------------------------------------------
// gemm_all — UNPINNED interior: R1 geometry (8 waves, 256-wide tiles, BK=64,
// 3-deep LDS ring, counted vmcnt) but only ONE fence per K-tile:
//   { vmcnt(N) ; sched_barrier ; s_barrier ; sched_barrier }
// Interior (ds_reads, GLDS stage, MFMAs) is left to the compiler, which
// emits counted lgkmcnt waits and pipelines LDS reads into the MFMA
// clusters (m97 evidence). The manual lgkmcnt(0)+sched_barrier pins that
// serialized read-service vs MFMA (30% MfmaUtil plateau) are removed.
__global__ __launch_bounds__(512, 2) void gemm_all(
    const signed char* __restrict__ Xq, const signed char* __restrict__ WcatT,
    const signed char* __restrict__ Q1, const signed char* __restrict__ Q2,
    const signed char* __restrict__ Wgb,
    const float* __restrict__ s_arr, const float* __restrict__ s1_arr,
    const float* __restrict__ b_f, const float* __restrict__ b_c,
    const float* __restrict__ b_g,
    unsigned short* __restrict__ FCG,   // (4096 x 6144) fp16
    unsigned short* __restrict__ U,     // cg*x  fp16
    unsigned short* __restrict__ V)     // 1-cg  fp16
{
    extern __shared__ __align__(16) signed char lds[];
    int bid = blockIdx.x;
    int grp = bid / 5, r5 = bid % 5;
    int tid = threadIdx.x;
    int lane = tid & 63, wv = tid >> 6;          // 8 waves
    int lr = lane & 15, lq = lane >> 4;
    int srow = wv * 16 + (lane >> 2);            // 0..127
    int ssw  = ((lane & 3) ^ ((srow >> 1) & 3)) * 16;
    const size_t ustep = (size_t)128 * DIM;

    if (r5 < 3) {
        // ---- fcg: 256x256 tile, 8 waves of 128x64 ----
        int fb = grp * 3 + r5;                   // 0..383
        int m0 = (fb & 15) * 256;
        int n0 = (fb >> 4) * 256;
        int wm = (wv >> 2) * 128;
        int wn = (wv & 3) * 64;
        const signed char* Ab = Xq + (size_t)m0 * DIM;
        const signed char* Bb = WcatT + (size_t)n0 * DIM;
        const signed char* gA = Ab + (size_t)srow * DIM + ssw;
        const signed char* gB = Bb + (size_t)srow * DIM + ssw;

        int4v acc[8][4] = {};
        int4v a[4], b[4];

        // prologue: tiles 0,1 -> ring buffers 0,1 (4 loads/thread per tile)
#pragma unroll
        for (int t0 = 0; t0 < 2; ++t0) {
            signed char* sb = lds + t0 * 32768;
            GLDS(gA + t0 * 64,         sb + wv * 1024);
            GLDS(gA + ustep + t0 * 64, sb + 8192 + wv * 1024);
            GLDS(gB + t0 * 64,         sb + 16384 + wv * 1024);
            GLDS(gB + ustep + t0 * 64, sb + 16384 + 8192 + wv * 1024);
        }

        int bc = 0, bn = 1, bs = 2;
        for (int t = 0; t < NT; ++t) {
            // single fence per K-tile: counted vmcnt + barrier (stage protocol)
            if (t == NT - 1) { asm volatile("s_waitcnt vmcnt(0)" ::: "memory"); }
            else             { asm volatile("s_waitcnt vmcnt(4)" ::: "memory"); }
            __builtin_amdgcn_sched_barrier(0);
            __builtin_amdgcn_s_barrier();
            __builtin_amdgcn_sched_barrier(0);
            const signed char* cA = lds + bc * 32768;
            const signed char* cB = cA + 16384;
            signed char* sA = lds + bs * 32768;
            signed char* sB = sA + 16384;
            int kt2 = (t + 2) * 64;
            bool st = (t + 2 < NT);

            // interior: compiler-scheduled (counted lgkm waits, read/MFMA overlap)
#pragma unroll
            for (int i = 0; i < 4; ++i) a[i] = frag_ld(cA, wm + i * 16 + lr, lq);
#pragma unroll
            for (int j = 0; j < 4; ++j) b[j] = frag_ld(cB, wn + j * 16 + lr, lq);
            if (st) {
                GLDS(gA + kt2,         sA + wv * 1024);
                GLDS(gA + ustep + kt2, sA + 8192 + wv * 1024);
            }
#pragma unroll
            for (int i = 0; i < 4; ++i)
#pragma unroll
                for (int j = 0; j < 4; ++j)
                    acc[i][j] = __builtin_amdgcn_mfma_i32_16x16x64_i8(
                        a[i], b[j], acc[i][j], 0, 0, 0);
#pragma unroll
            for (int i = 0; i < 4; ++i) a[i] = frag_ld(cA, wm + (4 + i) * 16 + lr, lq);
            if (st) {
                GLDS(gB + kt2,         sB + wv * 1024);
                GLDS(gB + ustep + kt2, sB + 8192 + wv * 1024);
            }
#pragma unroll
            for (int i = 0; i < 4; ++i)
#pragma unroll
                for (int j = 0; j < 4; ++j)
                    acc[4 + i][j] = __builtin_amdgcn_mfma_i32_16x16x64_i8(
                        a[i], b[j], acc[4 + i][j], 0, 0, 0);

            int tmp = bc; bc = bn; bn = bs; bs = tmp;
        }

        // epilogue (math identical to verified kernel)
        int rowb = m0 + wm;
#pragma unroll
        for (int mi = 0; mi < 8; ++mi) {
            float rinv[4];
#pragma unroll
            for (int r = 0; r < 4; ++r)
                rinv[r] = __builtin_amdgcn_rcpf(s_arr[rowb + mi * 16 + lq * 4 + r]);
#pragma unroll
            for (int ni = 0; ni < 4; ++ni) {
                int gcol = n0 + wn + ni * 16 + lr;
                int sec = gcol >> 11;
                int jj = gcol & 2047;
                float bias = (sec == 0) ? b_f[jj] : (sec == 1) ? b_c[jj] : b_g[jj];
#pragma unroll
                for (int r = 0; r < 4; ++r) {
                    int grow = rowb + mi * 16 + lq * 4 + r;
                    float z = fmaf((float)acc[mi][ni][r], rinv[r], bias);
                    float sg = fast_sigmoid(z);
                    FCG[(size_t)grow * NCAT + gcol] = f2h((sec == 1) ? z * sg : sg);
                }
            }
        }
    } else {
        // ---- cg: 256x128 tile, 8 waves of 128x32, two i8 planes ----
        int cb = grp * 2 + (r5 - 3);             // 0..255
        int m0 = (cb & 15) * 256;
        int n0 = (cb >> 4) * 128;
        int wm = (wv >> 2) * 128;
        int wn = (wv & 3) * 32;
        const signed char* A1b = Q1 + (size_t)m0 * DIM;
        const signed char* A2b = Q2 + (size_t)m0 * DIM;
        const signed char* Bb  = Wgb + (size_t)n0 * DIM;
        const signed char* g1 = A1b + (size_t)srow * DIM + ssw;
        const signed char* g2 = A2b + (size_t)srow * DIM + ssw;
        const signed char* gB = Bb + (size_t)srow * DIM + ssw;

        int4v acc1[8][2] = {};
        int4v acc2[8][2] = {};
        int4v a1[8], a2[8], b[2];

        // prologue: tiles 0,1 (5 loads/thread per tile)
#pragma unroll
        for (int t0 = 0; t0 < 2; ++t0) {
            signed char* sb = lds + t0 * 40960;
            GLDS(g1 + t0 * 64,         sb + wv * 1024);
            GLDS(g1 + ustep + t0 * 64, sb + 8192 + wv * 1024);
            GLDS(gB + t0 * 64,         sb + 32768 + wv * 1024);
            GLDS(g2 + t0 * 64,         sb + 16384 + wv * 1024);
            GLDS(g2 + ustep + t0 * 64, sb + 16384 + 8192 + wv * 1024);
        }

        int bc = 0, bn = 1, bs = 2;
        for (int t = 0; t < NT; ++t) {
            if (t == NT - 1) { asm volatile("s_waitcnt vmcnt(0)" ::: "memory"); }
            else             { asm volatile("s_waitcnt vmcnt(5)" ::: "memory"); }
            __builtin_amdgcn_sched_barrier(0);
            __builtin_amdgcn_s_barrier();
            __builtin_amdgcn_sched_barrier(0);
            const signed char* cA1 = lds + bc * 40960;
            const signed char* cA2 = cA1 + 16384;
            const signed char* cB  = cA1 + 32768;
            signed char* s1p = lds + bs * 40960;
            signed char* s2p = s1p + 16384;
            signed char* sBp = s1p + 32768;
            int kt2 = (t + 2) * 64;
            bool st = (t + 2 < NT);

#pragma unroll
            for (int i = 0; i < 8; ++i) a1[i] = frag_ld(cA1, wm + i * 16 + lr, lq);
#pragma unroll
            for (int j = 0; j < 2; ++j) b[j] = frag_ld(cB, wn + j * 16 + lr, lq);
            if (st) {
                GLDS(g1 + kt2,         s1p + wv * 1024);
                GLDS(g1 + ustep + kt2, s1p + 8192 + wv * 1024);
                GLDS(gB + kt2,         sBp + wv * 1024);
            }
#pragma unroll
            for (int i = 0; i < 8; ++i)
#pragma unroll
                for (int j = 0; j < 2; ++j)
                    acc1[i][j] = __builtin_amdgcn_mfma_i32_16x16x64_i8(
                        a1[i], b[j], acc1[i][j], 0, 0, 0);
#pragma unroll
            for (int i = 0; i < 8; ++i) a2[i] = frag_ld(cA2, wm + i * 16 + lr, lq);
            if (st) {
                GLDS(g2 + kt2,         s2p + wv * 1024);
                GLDS(g2 + ustep + kt2, s2p + 8192 + wv * 1024);
            }
#pragma unroll
            for (int i = 0; i < 8; ++i)
#pragma unroll
                for (int j = 0; j < 2; ++j)
                    acc2[i][j] = __builtin_amdgcn_mfma_i32_16x16x64_i8(
                        a2[i], b[j], acc2[i][j], 0, 0, 0);

            int tmp = bc; bc = bn; bn = bs; bs = tmp;
        }

        // epilogue (math identical to verified kernel)
        int rowb = m0 + wm;
#pragma unroll
        for (int mi = 0; mi < 8; ++mi) {
            float rinv[4];
#pragma unroll
            for (int r = 0; r < 4; ++r)
                rinv[r] = __builtin_amdgcn_rcpf(s1_arr[rowb + mi * 16 + lq * 4 + r]);
#pragma unroll
            for (int ni = 0; ni < 2; ++ni) {
                int gcol = n0 + wn + ni * 16 + lr;
#pragma unroll
                for (int r = 0; r < 4; ++r) {
                    int grow = rowb + mi * 16 + lq * 4 + r;
                    size_t go = (size_t)grow * DIM + gcol;
                    float zs = (float)acc1[mi][ni][r] + (float)acc2[mi][ni][r] * (1.f / 256.f);
                    float cg = fast_sigmoid(zs * rinv[r]);
                    float xv = ((float)Q1[go] + (float)Q2[go] * (1.f / 256.f)) * rinv[r];
                    U[go] = f2h(cg * xv);
                    V[go] = f2h(1.f - cg);
                }
            }
        }
    }
}

// ---------------------------------------------------------------------------
// Scan phase 1: 2 chains/thread, TCHUNK=16 (992 blocks; last chunk's summary
// is never consumed, so grid.y = NCHUNK-1).
__global__ __launch_bounds__(256) void scan_partial(
    const unsigned short* __restrict__ FCG, const unsigned short* __restrict__ U,
    const unsigned short* __restrict__ V, float4* __restrict__ PQ4)
{
    int tp = blockIdx.x * 256 + threadIdx.x;   // pair 0..1023
    int c = blockIdx.y;
    int b = blockIdx.z;
    int h0 = tp * 2;
    size_t r0 = (size_t)(b * 512 + c * TCHUNK);
    const unsigned short* fp = FCG + r0 * NCAT + h0;
    const unsigned short* up = U + r0 * DIM + h0;
    const unsigned short* vp = V + r0 * DIM + h0;
    float P0 = 1.f, Q0 = 0.f, P1 = 1.f, Q1v = 0.f;
#pragma unroll 4
    for (int t = 0; t < TCHUNK; ++t) {
        unsigned fw = *(const unsigned*)(fp);
        unsigned cw = *(const unsigned*)(fp + 2048);
        unsigned uw = *(const unsigned*)(up);
        unsigned vw = *(const unsigned*)(vp);
        float f0 = h2f(fw & 0xffff), f1 = h2f(fw >> 16);
        float c0 = h2f(cw & 0xffff), c1 = h2f(cw >> 16);
        float u0 = h2f(uw & 0xffff), u1 = h2f(uw >> 16);
        float v0 = h2f(vw & 0xffff), v1 = h2f(vw >> 16);
        float A0 = v0 * f0, A1 = v1 * f1;
        float B0 = fmaf(v0 * (1.f - f0), c0, u0);
        float B1 = fmaf(v1 * (1.f - f1), c1, u1);
        P0 = A0 * P0; Q0 = fmaf(A0, Q0, B0);
        P1 = A1 * P1; Q1v = fmaf(A1, Q1v, B1);
        fp += NCAT; up += DIM; vp += DIM;
    }
    float4 o; o.x = P0; o.y = Q0; o.z = P1; o.w = Q1v;
    PQ4[(size_t)c * 8192 + b * 1024 + tp] = o;
}

// Scan phase 3: recombine chunk summaries, then replay TCHUNK=16 steps and
// emit o_t (fp32).
__global__ __launch_bounds__(256) void scan_final(
    const unsigned short* __restrict__ FCG, const unsigned short* __restrict__ U,
    const unsigned short* __restrict__ V, const float4* __restrict__ PQ4,
    float* __restrict__ out)
{
    int tp = blockIdx.x * 256 + threadIdx.x;
    int c = blockIdx.y;
    int b = blockIdx.z;
    int h0 = tp * 2;
    float h0s = 0.f, h1s = 0.f;
#pragma unroll 4
    for (int cc = 0; cc < c; ++cc) {
        float4 pq = PQ4[(size_t)cc * 8192 + b * 1024 + tp];
        h0s = fmaf(pq.x, h0s, pq.y);
        h1s = fmaf(pq.z, h1s, pq.w);
    }
    size_t r0 = (size_t)(b * 512 + c * TCHUNK);
    const unsigned short* fp = FCG + r0 * NCAT + h0;
    const unsigned short* up = U + r0 * DIM + h0;
    const unsigned short* vp = V + r0 * DIM + h0;
    float* op = out + r0 * DIM + h0;
#pragma unroll 4
    for (int t = 0; t < TCHUNK; ++t) {
        unsigned fw = *(const unsigned*)(fp);
        unsigned cw = *(const unsigned*)(fp + 2048);
        unsigned gw = *(const unsigned*)(fp + 4096);
        unsigned uw = *(const unsigned*)(up);
        unsigned vw = *(const unsigned*)(vp);
        float f0 = h2f(fw & 0xffff), f1 = h2f(fw >> 16);
        float c0 = h2f(cw & 0xffff), c1 = h2f(cw >> 16);
        float g0 = h2f(gw & 0xffff), g1 = h2f(gw >> 16);
        float u0 = h2f(uw & 0xffff), u1 = h2f(uw >> 16);
        float v0 = h2f(vw & 0xffff), v1 = h2f(vw >> 16);
        float hn0 = f0 * h0s + (1.f - f0) * c0;
        float hn1 = f1 * h1s + (1.f - f1) * c1;
        float2 ov; ov.x = g0 * hn0; ov.y = g1 * hn1;
        *(float2*)op = ov;
        h0s = fmaf(v0, hn0, u0);
        h1s = fmaf(v1, hn1, u1);
        fp += NCAT; up += DIM; vp += DIM; op += DIM;
    }
}

// ---------------------------------------------------------------------------
extern "C" void kernel_launch(void* const* d_in, const int* in_sizes, int n_in,
                              void* d_out, int out_size, void* d_ws, size_t ws_size,
                              hipStream_t stream) {
    const float* x     = (const float*)d_in[0];
    const float* rmssc = (const float*)d_in[1];
    const float* W_f   = (const float*)d_in[2];
    const float* W_c   = (const float*)d_in[3];
    const float* W_g   = (const float*)d_in[4];
    const float* b_f   = (const float*)d_in[5];
    const float* b_c   = (const float*)d_in[6];
    const float* b_g   = (const float*)d_in[7];
    float* out = (float*)d_out;

    char* ws = (char*)d_ws;
    size_t off = 0;
    auto alloc = [&](size_t bytes) -> void* {
        void* p = ws + off;
        off += (bytes + 255) & ~(size_t)255;
        return p;
    };
    signed char* WcatT = (signed char*)alloc((size_t)NCAT * DIM);
    signed char* Wgb   = (signed char*)alloc((size_t)DIM * DIM);
    signed char* Xq    = (signed char*)alloc((size_t)RTOT * DIM);
    signed char* Q1    = (signed char*)alloc((size_t)RTOT * DIM);
    signed char* Q2    = (signed char*)alloc((size_t)RTOT * DIM);
    float* s_arr       = (float*)alloc((size_t)RTOT * 4);
    float* s1_arr      = (float*)alloc((size_t)RTOT * 4);
    unsigned short* FCG = (unsigned short*)alloc((size_t)RTOT * NCAT * 2);
    unsigned short* U   = (unsigned short*)alloc((size_t)RTOT * DIM * 2);
    unsigned short* V   = (unsigned short*)alloc((size_t)RTOT * DIM * 2);
    float4* PQ4        = (float4*)alloc((size_t)NCHUNK * 8192 * 16);

    // one-time opt-in for >64KB dynamic LDS (3-deep ring: cg path needs 120KB)
    static int gemm_attr_once = [](){
        return (int)hipFuncSetAttribute((const void*)gemm_all,
                   hipFuncAttributeMaxDynamicSharedMemorySize, 3 * 40960);
    }();
    (void)gemm_attr_once;

    hipLaunchKernelGGL(prep_all, dim3(5120), dim3(256), 0, stream,
                       x, rmssc, W_f, W_c, W_g, WcatT, Wgb, Xq, Q1, Q2,
                       s_arr, s1_arr);
    hipLaunchKernelGGL(gemm_all, dim3(640), dim3(512), 3 * 40960, stream,
                       Xq, WcatT, Q1, Q2, Wgb, s_arr, s1_arr,
                       b_f, b_c, b_g, FCG, U, V);
    hipLaunchKernelGGL(scan_partial, dim3(DIM / 512, NCHUNK - 1, 8), dim3(256), 0, stream,
                       FCG, U, V, PQ4);
    hipLaunchKernelGGL(scan_final, dim3(DIM / 512, NCHUNK, 8), dim3(256), 0, stream,
                       FCG, U, V, PQ4, out);
}

// Round 8
// 266.071 us; speedup vs baseline: 1.0828x; 1.0171x over previous
//
#include <hip/hip_runtime.h>
#include <hip/hip_bf16.h>
#include <cstdint>
#include <cstddef>

// Shapes (fixed): B=8, S=512, E=H=2048.
#define RTOT 4096      // B*S rows
#define DIM  2048
#define NCAT 6144      // f | c | g column sections
#define NCHUNK 32      // scan chunks
#define TCHUNK 16      // timesteps per chunk
#define NT 32          // K-tiles per GEMM (2048/64)

typedef __attribute__((ext_vector_type(4))) int int4v;

__device__ __forceinline__ float fast_sigmoid(float z) {
    return __builtin_amdgcn_rcpf(1.0f + __expf(-z));
}
__device__ __forceinline__ unsigned short f2h(float f) {
    union { _Float16 h; unsigned short u; } v; v.h = (_Float16)f; return v.u;
}
__device__ __forceinline__ float h2f(unsigned short u) {
    union { _Float16 h; unsigned short u; } v; v.u = u; return (float)v.h;
}

// global -> LDS DMA, 16B/lane; dest = wave-uniform base + lane*16.
#define GLDS(gp, lp) __builtin_amdgcn_global_load_lds( \
    (__attribute__((address_space(1))) const void*)(gp), \
    (__attribute__((address_space(3))) void*)(lp), 16, 0, 0)

// LDS[r][slot s] = G[r][s ^ ((r>>1)&3)]  (0 bank conflicts, verified)
__device__ __forceinline__ int4v frag_ld(const signed char* p, int R, int lq) {
    return *(const int4v*)(p + R * 64 + ((lq ^ ((R >> 1) & 3)) * 16));
}

// ---------------------------------------------------------------------------
// prep_all: one branched kernel (unchanged).
__global__ __launch_bounds__(256) void prep_all(
    const float* __restrict__ x, const float* __restrict__ scale,
    const float* __restrict__ Wf, const float* __restrict__ Wc,
    const float* __restrict__ Wg,
    signed char* __restrict__ WcatT, signed char* __restrict__ Wgb,
    signed char* __restrict__ Xq, signed char* __restrict__ Q1,
    signed char* __restrict__ Q2, float* __restrict__ s_arr,
    float* __restrict__ s1_arr)
{
    __shared__ __align__(16) char smem[4224];
    int bid = blockIdx.x;
    int tid = threadIdx.x;
    if (bid < 3072) {
        signed char (*tile)[65] = (signed char(*)[65])smem;
        int j0 = (bid % 96) * 64;
        int k0 = (bid / 96) * 64;
        const float* W = (j0 < 2048) ? Wf : (j0 < 4096) ? Wc : Wg;
        int jb = j0 & 2047;
        int c  = tid & 63;
        int rr = tid >> 6;
#pragma unroll
        for (int p = 0; p < 16; ++p) {
            int kl = p * 4 + rr;
            tile[kl][c] = (signed char)(int)W[(size_t)(k0 + kl) * DIM + jb + c];
        }
        __syncthreads();
#pragma unroll
        for (int p = 0; p < 16; ++p) {
            int jl = p * 4 + rr;
            WcatT[(size_t)(j0 + jl) * DIM + k0 + c] = tile[c][jl];
        }
    } else if (bid < 4096) {
        int idx = (bid - 3072) * 4096 + tid * 16;
#pragma unroll
        for (int p = 0; p < 4; ++p) {
            float4 v = *(const float4*)(Wg + idx + p * 4);
            char4 o;
            o.x = (signed char)(int)v.x; o.y = (signed char)(int)v.y;
            o.z = (signed char)(int)v.z; o.w = (signed char)(int)v.w;
            *(char4*)(Wgb + idx + p * 4) = o;
        }
    } else {
        // one wave per row; 32 elems/lane; shuffle-only butterfly reductions
        int row = (bid - 4096) * 4 + (tid >> 6);
        int lane = tid & 63;
        const float* xr = x + (size_t)row * DIM;
        float xs[32], ys[32];
        float sum = 0.f, mx2 = 0.f;
#pragma unroll
        for (int sw = 0; sw < 4; ++sw) {
            int base = sw * 512 + lane * 8;
            float4 a0 = *(const float4*)(xr + base);
            float4 a1 = *(const float4*)(xr + base + 4);
            xs[sw * 8 + 0] = a0.x; xs[sw * 8 + 1] = a0.y;
            xs[sw * 8 + 2] = a0.z; xs[sw * 8 + 3] = a0.w;
            xs[sw * 8 + 4] = a1.x; xs[sw * 8 + 5] = a1.y;
            xs[sw * 8 + 6] = a1.z; xs[sw * 8 + 7] = a1.w;
        }
#pragma unroll
        for (int i = 0; i < 32; ++i) {
            sum += xs[i] * xs[i];
            mx2 = fmaxf(mx2, fabsf(xs[i]));
        }
#pragma unroll
        for (int off = 1; off < 64; off <<= 1) {
            sum += __shfl_xor(sum, off);
            mx2 = fmaxf(mx2, __shfl_xor(mx2, off));
        }
        float rms = 1.0f / sqrtf(sum * (1.0f / 2048.0f) + 1e-5f);
        float mx = 0.f;
#pragma unroll
        for (int sw = 0; sw < 4; ++sw) {
            int base = sw * 512 + lane * 8;
            float4 c0 = *(const float4*)(scale + base);
            float4 c1 = *(const float4*)(scale + base + 4);
            float scv[8] = {c0.x, c0.y, c0.z, c0.w, c1.x, c1.y, c1.z, c1.w};
#pragma unroll
            for (int i = 0; i < 8; ++i) {
                float yv = (xs[sw * 8 + i] * rms) * scv[i];
                ys[sw * 8 + i] = yv;
                mx = fmaxf(mx, fabsf(yv));
            }
        }
#pragma unroll
        for (int off = 1; off < 64; off <<= 1) mx = fmaxf(mx, __shfl_xor(mx, off));
        float s = 127.0f / (mx + 1e-5f);
        s = fminf(fmaxf(s, 0.001f), 1000.0f);
        float s1 = 127.0f / (mx2 + 1e-5f);
        float inv_s1 = 1.0f / s1;
        if (lane == 0) { s_arr[row] = s; s1_arr[row] = s1; }
#pragma unroll
        for (int sw = 0; sw < 4; ++sw) {
            signed char q8[8], q1b[8], q2b[8];
#pragma unroll
            for (int i = 0; i < 8; ++i) {
                float xv = xs[sw * 8 + i];
                float q = fminf(fmaxf(rintf(s * ys[sw * 8 + i]), -128.f), 127.f);
                q8[i] = (signed char)(int)q;
                float qq1 = fminf(fmaxf(rintf(s1 * xv), -128.f), 127.f);
                q1b[i] = (signed char)(int)qq1;
                float r = xv - qq1 * inv_s1;
                float qq2 = fminf(fmaxf(rintf(s1 * 256.f * r), -128.f), 127.f);
                q2b[i] = (signed char)(int)qq2;
            }
            size_t o = (size_t)row * DIM + sw * 512 + lane * 8;
            *(int2*)(Xq + o) = *(int2*)q8;
            *(int2*)(Q1 + o) = *(int2*)q1b;
            *(int2*)(Q2 + o) = *(int2*)q2b;
        }
    }
}

// ---------------------------------------------------------------------------
// gemm_all — R6 verified structure (unpinned interior, 3-deep ring, counted
// vmcnt, one barrier per K-tile) + XCD locality:
//   * chunked bijective swizzle lb = (bid&7)*80 + bid>>3 (640 = 8 x 80):
//     each XCD gets 80 consecutive logical blocks -> shared operand panels
//     stay in that XCD's private L2 (T1).
//   * cg tile map flipped to m-major so each XCD re-reads the SMALL Wgb
//     (4MB) instead of the large Q1+Q2 (16MB).
__global__ __launch_bounds__(512, 2) void gemm_all(
    const signed char* __restrict__ Xq, const signed char* __restrict__ WcatT,
    const signed char* __restrict__ Q1, const signed char* __restrict__ Q2,
    const signed char* __restrict__ Wgb,
    const float* __restrict__ s_arr, const float* __restrict__ s1_arr,
    const float* __restrict__ b_f, const float* __restrict__ b_c,
    const float* __restrict__ b_g,
    unsigned short* __restrict__ FCG,   // (4096 x 6144) fp16
    unsigned short* __restrict__ U,     // cg*x  fp16
    unsigned short* __restrict__ V)     // 1-cg  fp16
{
    extern __shared__ __align__(16) signed char lds[];
    // XCD-chunked bijective swizzle: 640 blocks = 8 XCDs x 80
    int lbid = (blockIdx.x & 7) * 80 + (blockIdx.x >> 3);
    int grp = lbid / 5, r5 = lbid % 5;
    int tid = threadIdx.x;
    int lane = tid & 63, wv = tid >> 6;          // 8 waves
    int lr = lane & 15, lq = lane >> 4;
    int srow = wv * 16 + (lane >> 2);            // 0..127
    int ssw  = ((lane & 3) ^ ((srow >> 1) & 3)) * 16;
    const size_t ustep = (size_t)128 * DIM;

    if (r5 < 3) {
        // ---- fcg: 256x256 tile, 8 waves of 128x64 (n-major: B-panel local) ----
        int fb = grp * 3 + r5;                   // 0..383
        int m0 = (fb & 15) * 256;
        int n0 = (fb >> 4) * 256;
        int wm = (wv >> 2) * 128;
        int wn = (wv & 3) * 64;
        const signed char* Ab = Xq + (size_t)m0 * DIM;
        const signed char* Bb = WcatT + (size_t)n0 * DIM;
        const signed char* gA = Ab + (size_t)srow * DIM + ssw;
        const signed char* gB = Bb + (size_t)srow * DIM + ssw;

        int4v acc[8][4] = {};
        int4v a[4], b[4];

        // prologue: tiles 0,1 -> ring buffers 0,1 (4 loads/thread per tile)
#pragma unroll
        for (int t0 = 0; t0 < 2; ++t0) {
            signed char* sb = lds + t0 * 32768;
            GLDS(gA + t0 * 64,         sb + wv * 1024);
            GLDS(gA + ustep + t0 * 64, sb + 8192 + wv * 1024);
            GLDS(gB + t0 * 64,         sb + 16384 + wv * 1024);
            GLDS(gB + ustep + t0 * 64, sb + 16384 + 8192 + wv * 1024);
        }

        int bc = 0, bn = 1, bs = 2;
        for (int t = 0; t < NT; ++t) {
            // single fence per K-tile: counted vmcnt + barrier (stage protocol)
            if (t == NT - 1) { asm volatile("s_waitcnt vmcnt(0)" ::: "memory"); }
            else             { asm volatile("s_waitcnt vmcnt(4)" ::: "memory"); }
            __builtin_amdgcn_sched_barrier(0);
            __builtin_amdgcn_s_barrier();
            __builtin_amdgcn_sched_barrier(0);
            const signed char* cA = lds + bc * 32768;
            const signed char* cB = cA + 16384;
            signed char* sA = lds + bs * 32768;
            signed char* sB = sA + 16384;
            int kt2 = (t + 2) * 64;
            bool st = (t + 2 < NT);

            // interior: compiler-scheduled (counted lgkm waits, read/MFMA overlap)
#pragma unroll
            for (int i = 0; i < 4; ++i) a[i] = frag_ld(cA, wm + i * 16 + lr, lq);
#pragma unroll
            for (int j = 0; j < 4; ++j) b[j] = frag_ld(cB, wn + j * 16 + lr, lq);
            if (st) {
                GLDS(gA + kt2,         sA + wv * 1024);
                GLDS(gA + ustep + kt2, sA + 8192 + wv * 1024);
            }
#pragma unroll
            for (int i = 0; i < 4; ++i)
#pragma unroll
                for (int j = 0; j < 4; ++j)
                    acc[i][j] = __builtin_amdgcn_mfma_i32_16x16x64_i8(
                        a[i], b[j], acc[i][j], 0, 0, 0);
#pragma unroll
            for (int i = 0; i < 4; ++i) a[i] = frag_ld(cA, wm + (4 + i) * 16 + lr, lq);
            if (st) {
                GLDS(gB + kt2,         sB + wv * 1024);
                GLDS(gB + ustep + kt2, sB + 8192 + wv * 1024);
            }
#pragma unroll
            for (int i = 0; i < 4; ++i)
#pragma unroll
                for (int j = 0; j < 4; ++j)
                    acc[4 + i][j] = __builtin_amdgcn_mfma_i32_16x16x64_i8(
                        a[i], b[j], acc[4 + i][j], 0, 0, 0);

            int tmp = bc; bc = bn; bn = bs; bs = tmp;
        }

        // epilogue (math identical to verified kernel)
        int rowb = m0 + wm;
#pragma unroll
        for (int mi = 0; mi < 8; ++mi) {
            float rinv[4];
#pragma unroll
            for (int r = 0; r < 4; ++r)
                rinv[r] = __builtin_amdgcn_rcpf(s_arr[rowb + mi * 16 + lq * 4 + r]);
#pragma unroll
            for (int ni = 0; ni < 4; ++ni) {
                int gcol = n0 + wn + ni * 16 + lr;
                int sec = gcol >> 11;
                int jj = gcol & 2047;
                float bias = (sec == 0) ? b_f[jj] : (sec == 1) ? b_c[jj] : b_g[jj];
#pragma unroll
                for (int r = 0; r < 4; ++r) {
                    int grow = rowb + mi * 16 + lq * 4 + r;
                    float z = fmaf((float)acc[mi][ni][r], rinv[r], bias);
                    float sg = fast_sigmoid(z);
                    FCG[(size_t)grow * NCAT + gcol] = f2h((sec == 1) ? z * sg : sg);
                }
            }
        }
    } else {
        // ---- cg: 256x128 tile, 8 waves of 128x32, two i8 planes ----
        // m-major map: consecutive blocks share the A (Q1/Q2) panel; each XCD
        // re-reads the small Wgb instead of the 16MB A planes.
        int cb = grp * 2 + (r5 - 3);             // 0..255
        int m0 = (cb >> 4) * 256;                // 16 m-tiles (slow)
        int n0 = (cb & 15) * 128;                // 16 n-tiles (fast)
        int wm = (wv >> 2) * 128;
        int wn = (wv & 3) * 32;
        const signed char* A1b = Q1 + (size_t)m0 * DIM;
        const signed char* A2b = Q2 + (size_t)m0 * DIM;
        const signed char* Bb  = Wgb + (size_t)n0 * DIM;
        const signed char* g1 = A1b + (size_t)srow * DIM + ssw;
        const signed char* g2 = A2b + (size_t)srow * DIM + ssw;
        const signed char* gB = Bb + (size_t)srow * DIM + ssw;

        int4v acc1[8][2] = {};
        int4v acc2[8][2] = {};
        int4v a1[8], a2[8], b[2];

        // prologue: tiles 0,1 (5 loads/thread per tile)
#pragma unroll
        for (int t0 = 0; t0 < 2; ++t0) {
            signed char* sb = lds + t0 * 40960;
            GLDS(g1 + t0 * 64,         sb + wv * 1024);
            GLDS(g1 + ustep + t0 * 64, sb + 8192 + wv * 1024);
            GLDS(gB + t0 * 64,         sb + 32768 + wv * 1024);
            GLDS(g2 + t0 * 64,         sb + 16384 + wv * 1024);
            GLDS(g2 + ustep + t0 * 64, sb + 16384 + 8192 + wv * 1024);
        }

        int bc = 0, bn = 1, bs = 2;
        for (int t = 0; t < NT; ++t) {
            if (t == NT - 1) { asm volatile("s_waitcnt vmcnt(0)" ::: "memory"); }
            else             { asm volatile("s_waitcnt vmcnt(5)" ::: "memory"); }
            __builtin_amdgcn_sched_barrier(0);
            __builtin_amdgcn_s_barrier();
            __builtin_amdgcn_sched_barrier(0);
            const signed char* cA1 = lds + bc * 40960;
            const signed char* cA2 = cA1 + 16384;
            const signed char* cB  = cA1 + 32768;
            signed char* s1p = lds + bs * 40960;
            signed char* s2p = s1p + 16384;
            signed char* sBp = s1p + 32768;
            int kt2 = (t + 2) * 64;
            bool st = (t + 2 < NT);

#pragma unroll
            for (int i = 0; i < 8; ++i) a1[i] = frag_ld(cA1, wm + i * 16 + lr, lq);
#pragma unroll
            for (int j = 0; j < 2; ++j) b[j] = frag_ld(cB, wn + j * 16 + lr, lq);
            if (st) {
                GLDS(g1 + kt2,         s1p + wv * 1024);
                GLDS(g1 + ustep + kt2, s1p + 8192 + wv * 1024);
                GLDS(gB + kt2,         sBp + wv * 1024);
            }
#pragma unroll
            for (int i = 0; i < 8; ++i)
#pragma unroll
                for (int j = 0; j < 2; ++j)
                    acc1[i][j] = __builtin_amdgcn_mfma_i32_16x16x64_i8(
                        a1[i], b[j], acc1[i][j], 0, 0, 0);
#pragma unroll
            for (int i = 0; i < 8; ++i) a2[i] = frag_ld(cA2, wm + i * 16 + lr, lq);
            if (st) {
                GLDS(g2 + kt2,         s2p + wv * 1024);
                GLDS(g2 + ustep + kt2, s2p + 8192 + wv * 1024);
            }
#pragma unroll
            for (int i = 0; i < 8; ++i)
#pragma unroll
                for (int j = 0; j < 2; ++j)
                    acc2[i][j] = __builtin_amdgcn_mfma_i32_16x16x64_i8(
                        a2[i], b[j], acc2[i][j], 0, 0, 0);

            int tmp = bc; bc = bn; bn = bs; bs = tmp;
        }

        // epilogue (math identical to verified kernel)
        int rowb = m0 + wm;
#pragma unroll
        for (int mi = 0; mi < 8; ++mi) {
            float rinv[4];
#pragma unroll
            for (int r = 0; r < 4; ++r)
                rinv[r] = __builtin_amdgcn_rcpf(s1_arr[rowb + mi * 16 + lq * 4 + r]);
#pragma unroll
            for (int ni = 0; ni < 2; ++ni) {
                int gcol = n0 + wn + ni * 16 + lr;
#pragma unroll
                for (int r = 0; r < 4; ++r) {
                    int grow = rowb + mi * 16 + lq * 4 + r;
                    size_t go = (size_t)grow * DIM + gcol;
                    float zs = (float)acc1[mi][ni][r] + (float)acc2[mi][ni][r] * (1.f / 256.f);
                    float cg = fast_sigmoid(zs * rinv[r]);
                    float xv = ((float)Q1[go] + (float)Q2[go] * (1.f / 256.f)) * rinv[r];
                    U[go] = f2h(cg * xv);
                    V[go] = f2h(1.f - cg);
                }
            }
        }
    }
}

// ---------------------------------------------------------------------------
// Scan phase 1: 2 chains/thread, TCHUNK=16 (992 blocks; last chunk's summary
// is never consumed, so grid.y = NCHUNK-1).
__global__ __launch_bounds__(256) void scan_partial(
    const unsigned short* __restrict__ FCG, const unsigned short* __restrict__ U,
    const unsigned short* __restrict__ V, float4* __restrict__ PQ4)
{
    int tp = blockIdx.x * 256 + threadIdx.x;   // pair 0..1023
    int c = blockIdx.y;
    int b = blockIdx.z;
    int h0 = tp * 2;
    size_t r0 = (size_t)(b * 512 + c * TCHUNK);
    const unsigned short* fp = FCG + r0 * NCAT + h0;
    const unsigned short* up = U + r0 * DIM + h0;
    const unsigned short* vp = V + r0 * DIM + h0;
    float P0 = 1.f, Q0 = 0.f, P1 = 1.f, Q1v = 0.f;
#pragma unroll 4
    for (int t = 0; t < TCHUNK; ++t) {
        unsigned fw = *(const unsigned*)(fp);
        unsigned cw = *(const unsigned*)(fp + 2048);
        unsigned uw = *(const unsigned*)(up);
        unsigned vw = *(const unsigned*)(vp);
        float f0 = h2f(fw & 0xffff), f1 = h2f(fw >> 16);
        float c0 = h2f(cw & 0xffff), c1 = h2f(cw >> 16);
        float u0 = h2f(uw & 0xffff), u1 = h2f(uw >> 16);
        float v0 = h2f(vw & 0xffff), v1 = h2f(vw >> 16);
        float A0 = v0 * f0, A1 = v1 * f1;
        float B0 = fmaf(v0 * (1.f - f0), c0, u0);
        float B1 = fmaf(v1 * (1.f - f1), c1, u1);
        P0 = A0 * P0; Q0 = fmaf(A0, Q0, B0);
        P1 = A1 * P1; Q1v = fmaf(A1, Q1v, B1);
        fp += NCAT; up += DIM; vp += DIM;
    }
    float4 o; o.x = P0; o.y = Q0; o.z = P1; o.w = Q1v;
    PQ4[(size_t)c * 8192 + b * 1024 + tp] = o;
}

// Scan phase 3: recombine chunk summaries, then replay TCHUNK=16 steps and
// emit o_t (fp32).
__global__ __launch_bounds__(256) void scan_final(
    const unsigned short* __restrict__ FCG, const unsigned short* __restrict__ U,
    const unsigned short* __restrict__ V, const float4* __restrict__ PQ4,
    float* __restrict__ out)
{
    int tp = blockIdx.x * 256 + threadIdx.x;
    int c = blockIdx.y;
    int b = blockIdx.z;
    int h0 = tp * 2;
    float h0s = 0.f, h1s = 0.f;
#pragma unroll 4
    for (int cc = 0; cc < c; ++cc) {
        float4 pq = PQ4[(size_t)cc * 8192 + b * 1024 + tp];
        h0s = fmaf(pq.x, h0s, pq.y);
        h1s = fmaf(pq.z, h1s, pq.w);
    }
    size_t r0 = (size_t)(b * 512 + c * TCHUNK);
    const unsigned short* fp = FCG + r0 * NCAT + h0;
    const unsigned short* up = U + r0 * DIM + h0;
    const unsigned short* vp = V + r0 * DIM + h0;
    float* op = out + r0 * DIM + h0;
#pragma unroll 4
    for (int t = 0; t < TCHUNK; ++t) {
        unsigned fw = *(const unsigned*)(fp);
        unsigned cw = *(const unsigned*)(fp + 2048);
        unsigned gw = *(const unsigned*)(fp + 4096);
        unsigned uw = *(const unsigned*)(up);
        unsigned vw = *(const unsigned*)(vp);
        float f0 = h2f(fw & 0xffff), f1 = h2f(fw >> 16);
        float c0 = h2f(cw & 0xffff), c1 = h2f(cw >> 16);
        float g0 = h2f(gw & 0xffff), g1 = h2f(gw >> 16);
        float u0 = h2f(uw & 0xffff), u1 = h2f(uw >> 16);
        float v0 = h2f(vw & 0xffff), v1 = h2f(vw >> 16);
        float hn0 = f0 * h0s + (1.f - f0) * c0;
        float hn1 = f1 * h1s + (1.f - f1) * c1;
        float2 ov; ov.x = g0 * hn0; ov.y = g1 * hn1;
        *(float2*)op = ov;
        h0s = fmaf(v0, hn0, u0);
        h1s = fmaf(v1, hn1, u1);
        fp += NCAT; up += DIM; vp += DIM; op += DIM;
    }
}

// ---------------------------------------------------------------------------
extern "C" void kernel_launch(void* const* d_in, const int* in_sizes, int n_in,
                              void* d_out, int out_size, void* d_ws, size_t ws_size,
                              hipStream_t stream) {
    const float* x     = (const float*)d_in[0];
    const float* rmssc = (const float*)d_in[1];
    const float* W_f   = (const float*)d_in[2];
    const float* W_c   = (const float*)d_in[3];
    const float* W_g   = (const float*)d_in[4];
    const float* b_f   = (const float*)d_in[5];
    const float* b_c   = (const float*)d_in[6];
    const float* b_g   = (const float*)d_in[7];
    float* out = (float*)d_out;

    char* ws = (char*)d_ws;
    size_t off = 0;
    auto alloc = [&](size_t bytes) -> void* {
        void* p = ws + off;
        off += (bytes + 255) & ~(size_t)255;
        return p;
    };
    signed char* WcatT = (signed char*)alloc((size_t)NCAT * DIM);
    signed char* Wgb   = (signed char*)alloc((size_t)DIM * DIM);
    signed char* Xq    = (signed char*)alloc((size_t)RTOT * DIM);
    signed char* Q1    = (signed char*)alloc((size_t)RTOT * DIM);
    signed char* Q2    = (signed char*)alloc((size_t)RTOT * DIM);
    float* s_arr       = (float*)alloc((size_t)RTOT * 4);
    float* s1_arr      = (float*)alloc((size_t)RTOT * 4);
    unsigned short* FCG = (unsigned short*)alloc((size_t)RTOT * NCAT * 2);
    unsigned short* U   = (unsigned short*)alloc((size_t)RTOT * DIM * 2);
    unsigned short* V   = (unsigned short*)alloc((size_t)RTOT * DIM * 2);
    float4* PQ4        = (float4*)alloc((size_t)NCHUNK * 8192 * 16);

    // one-time opt-in for >64KB dynamic LDS (3-deep ring: cg path needs 120KB)
    static int gemm_attr_once = [](){
        return (int)hipFuncSetAttribute((const void*)gemm_all,
                   hipFuncAttributeMaxDynamicSharedMemorySize, 3 * 40960);
    }();
    (void)gemm_attr_once;

    hipLaunchKernelGGL(prep_all, dim3(5120), dim3(256), 0, stream,
                       x, rmssc, W_f, W_c, W_g, WcatT, Wgb, Xq, Q1, Q2,
                       s_arr, s1_arr);
    hipLaunchKernelGGL(gemm_all, dim3(640), dim3(512), 3 * 40960, stream,
                       Xq, WcatT, Q1, Q2, Wgb, s_arr, s1_arr,
                       b_f, b_c, b_g, FCG, U, V);
    hipLaunchKernelGGL(scan_partial, dim3(DIM / 512, NCHUNK - 1, 8), dim3(256), 0, stream,
                       FCG, U, V, PQ4);
    hipLaunchKernelGGL(scan_final, dim3(DIM / 512, NCHUNK, 8), dim3(256), 0, stream,
                       FCG, U, V, PQ4, out);
}